// Round 1
// baseline (49.515 us; speedup 1.0000x reference)
//
#include <hip/hip_runtime.h>

#define NUM_FREQ 32
#define B_DIM 4
#define N_DIM 16
#define S_DIM 4096
#define FD_DIM 128
#define C_DIM 8
#define P_DIM 512  // S_DIM / C_DIM

// ---------------------------------------------------------------------------
// Kernel 1: build m5[b,c,f] = (L_f @ diag(exp(D_f)) @ U_f) @ matrix[b,c]
// 4*8*32 = 1024 matrices of 4x4 fp32 -> 64 KB in d_ws.
// ---------------------------------------------------------------------------
__global__ void build_m5_kernel(const float* __restrict__ matrix,
                                const float* __restrict__ L_params,
                                const float* __restrict__ D_params,
                                const float* __restrict__ U_params,
                                float* __restrict__ m5) {
    int idx = blockIdx.x * blockDim.x + threadIdx.x;
    const int total = B_DIM * C_DIM * NUM_FREQ;
    if (idx >= total) return;

    int f  = idx & (NUM_FREQ - 1);
    int bc = idx >> 5;             // b*8 + c

    const float l0 = L_params[f * 6 + 0];
    const float l1 = L_params[f * 6 + 1];
    const float l2 = L_params[f * 6 + 2];
    const float l3 = L_params[f * 6 + 3];
    const float l4 = L_params[f * 6 + 4];
    const float l5 = L_params[f * 6 + 5];

    const float e0 = __expf(D_params[f * 4 + 0]);
    const float e1 = __expf(D_params[f * 4 + 1]);
    const float e2 = __expf(D_params[f * 4 + 2]);
    const float e3 = __expf(D_params[f * 4 + 3]);

    const float u0 = U_params[f * 6 + 0];
    const float u1 = U_params[f * 6 + 1];
    const float u2 = U_params[f * 6 + 2];
    const float u3 = U_params[f * 6 + 3];
    const float u4 = U_params[f * 6 + 4];
    const float u5 = U_params[f * 6 + 5];

    // freq[i][k] = sum_j L[i][j] * e[j] * U[j][k]
    // U rows: U0=[1,u0,u1,u2] U1=[0,1,u3,u4] U2=[0,0,1,u5] U3=[0,0,0,1]
    float fr[4][4];
    // row 0: e0 * U0
    fr[0][0] = e0;       fr[0][1] = e0 * u0;  fr[0][2] = e0 * u1;          fr[0][3] = e0 * u2;
    // row 1: l0*e0*U0 + e1*U1
    fr[1][0] = l0 * e0;
    fr[1][1] = l0 * e0 * u0 + e1;
    fr[1][2] = l0 * e0 * u1 + e1 * u3;
    fr[1][3] = l0 * e0 * u2 + e1 * u4;
    // row 2: l1*e0*U0 + l2*e1*U1 + e2*U2
    fr[2][0] = l1 * e0;
    fr[2][1] = l1 * e0 * u0 + l2 * e1;
    fr[2][2] = l1 * e0 * u1 + l2 * e1 * u3 + e2;
    fr[2][3] = l1 * e0 * u2 + l2 * e1 * u4 + e2 * u5;
    // row 3: l3*e0*U0 + l4*e1*U1 + l5*e2*U2 + e3*U3
    fr[3][0] = l3 * e0;
    fr[3][1] = l3 * e0 * u0 + l4 * e1;
    fr[3][2] = l3 * e0 * u1 + l4 * e1 * u3 + l5 * e2;
    fr[3][3] = l3 * e0 * u2 + l4 * e1 * u4 + l5 * e2 * u5 + e3;

    // M = fr @ matrix[bc] ; matrix row-major [4][4]
    const float* mt = matrix + bc * 16;
    float* out = m5 + idx * 16;
#pragma unroll
    for (int i = 0; i < 4; ++i) {
#pragma unroll
        for (int k = 0; k < 4; ++k) {
            out[i * 4 + k] = fr[i][0] * mt[0 * 4 + k]
                           + fr[i][1] * mt[1 * 4 + k]
                           + fr[i][2] * mt[2 * 4 + k]
                           + fr[i][3] * mt[3 * 4 + k];
        }
    }
}

// ---------------------------------------------------------------------------
// Kernel 2: streaming apply. One thread per float4 (one frequency group of 4).
// idx layout: ((b*16 + n)*4096 + s)*32 + f   (float4 units)
// out[..., i] = sum_j M[i][j] * v[j]
// ---------------------------------------------------------------------------
__global__ void __launch_bounds__(256)
apply_kernel(const float4* __restrict__ feats,
             const float* __restrict__ m5,
             float4* __restrict__ out) {
    const int idx = blockIdx.x * blockDim.x + threadIdx.x;
    // total float4 = 4*16*4096*32 = 8,388,608 ; grid sized exactly.

    const int f  = idx & 31;
    const int sp = idx >> 5;          // ((b*16+n)*4096 + s)
    const int s  = sp & 4095;
    const int b  = sp >> 16;          // sp / (16*4096)
    const int c  = s >> 9;            // s / 512

    const float4* M = reinterpret_cast<const float4*>(
        m5 + ((((b << 3) + c) << 5) + f) * 16);
    const float4 m0 = M[0];
    const float4 m1 = M[1];
    const float4 m2 = M[2];
    const float4 m3 = M[3];

    const float4 v = feats[idx];
    float4 o;
    o.x = m0.x * v.x + m0.y * v.y + m0.z * v.z + m0.w * v.w;
    o.y = m1.x * v.x + m1.y * v.y + m1.z * v.z + m1.w * v.w;
    o.z = m2.x * v.x + m2.y * v.y + m2.z * v.z + m2.w * v.w;
    o.w = m3.x * v.x + m3.y * v.y + m3.z * v.z + m3.w * v.w;
    out[idx] = o;
}

extern "C" void kernel_launch(void* const* d_in, const int* in_sizes, int n_in,
                              void* d_out, int out_size, void* d_ws, size_t ws_size,
                              hipStream_t stream) {
    const float* feats    = (const float*)d_in[0];
    const float* matrix   = (const float*)d_in[1];
    const float* L_params = (const float*)d_in[2];
    const float* D_params = (const float*)d_in[3];
    const float* U_params = (const float*)d_in[4];
    float* out = (float*)d_out;
    float* m5  = (float*)d_ws;   // 1024 * 16 floats = 64 KB

    // Build the 1024 combined 4x4 matrices.
    build_m5_kernel<<<4, 256, 0, stream>>>(matrix, L_params, D_params, U_params, m5);

    // Streaming apply: 8,388,608 float4 elements.
    const int total4 = (B_DIM * N_DIM * S_DIM * FD_DIM) / 4;
    const int block = 256;
    const int grid = total4 / block;   // 32768
    apply_kernel<<<grid, block, 0, stream>>>(
        reinterpret_cast<const float4*>(feats), m5,
        reinterpret_cast<float4*>(out));
}

// Round 3
// 46.829 us; speedup vs baseline: 1.0574x; 1.0574x over previous
//
#include <hip/hip_runtime.h>

#define NUM_FREQ 32
#define KU 4  // float4 elements per thread

typedef float vfloat4 __attribute__((ext_vector_type(4)));

// Fused kernel: each block of 256 threads processes 1024 consecutive float4
// (= 32 sp-rows of 32 freq-groups). All of them share one (b,c), so the block
// rebuilds the 32 combined matrices M[f] = (L_f diag(e^D_f) U_f) @ matrix[b,c]
// into LDS and streams feats -> out with copy-equivalent VMEM traffic.
__global__ void __launch_bounds__(256)
camfreq_fused_kernel(const vfloat4* __restrict__ feats,
                     const float* __restrict__ matrix,
                     const float* __restrict__ L_params,
                     const float* __restrict__ D_params,
                     const float* __restrict__ U_params,
                     vfloat4* __restrict__ out) {
    // LDS layout: m5[elem][f], elem = i*4+j (row-major 4x4), f = 0..31.
    // Readers: lane -> f = t&31 is consecutive -> conflict-free (2 lanes/bank broadcast).
    __shared__ float m5[16][NUM_FREQ];

    const int t = threadIdx.x;
    const int base = blockIdx.x * (256 * KU);   // float4 index base (max 2^23, fits int)

    // Shared (b,c) for the whole block.
    const int sp0 = base >> 5;        // (b*16+n)*4096 + s
    const int s0  = sp0 & 4095;
    const int b   = sp0 >> 16;
    const int c   = s0 >> 9;

    // Issue streaming loads FIRST so HBM latency hides under the m5 build.
    vfloat4 v[KU];
#pragma unroll
    for (int k = 0; k < KU; ++k) {
        v[k] = __builtin_nontemporal_load(&feats[base + k * 256 + t]);
    }

    // Threads 0..31: build M for frequency f = t.
    if (t < NUM_FREQ) {
        const int f = t;
        const float l0 = L_params[f * 6 + 0], l1 = L_params[f * 6 + 1];
        const float l2 = L_params[f * 6 + 2], l3 = L_params[f * 6 + 3];
        const float l4 = L_params[f * 6 + 4], l5 = L_params[f * 6 + 5];
        const float e0 = __expf(D_params[f * 4 + 0]);
        const float e1 = __expf(D_params[f * 4 + 1]);
        const float e2 = __expf(D_params[f * 4 + 2]);
        const float e3 = __expf(D_params[f * 4 + 3]);
        const float u0 = U_params[f * 6 + 0], u1 = U_params[f * 6 + 1];
        const float u2 = U_params[f * 6 + 2], u3 = U_params[f * 6 + 3];
        const float u4 = U_params[f * 6 + 4], u5 = U_params[f * 6 + 5];

        // freq[i][k] = sum_j L[i][j]*e[j]*U[j][k]
        float fr[4][4];
        fr[0][0] = e0;      fr[0][1] = e0 * u0;       fr[0][2] = e0 * u1;                 fr[0][3] = e0 * u2;
        fr[1][0] = l0 * e0;
        fr[1][1] = l0 * e0 * u0 + e1;
        fr[1][2] = l0 * e0 * u1 + e1 * u3;
        fr[1][3] = l0 * e0 * u2 + e1 * u4;
        fr[2][0] = l1 * e0;
        fr[2][1] = l1 * e0 * u0 + l2 * e1;
        fr[2][2] = l1 * e0 * u1 + l2 * e1 * u3 + e2;
        fr[2][3] = l1 * e0 * u2 + l2 * e1 * u4 + e2 * u5;
        fr[3][0] = l3 * e0;
        fr[3][1] = l3 * e0 * u0 + l4 * e1;
        fr[3][2] = l3 * e0 * u1 + l4 * e1 * u3 + l5 * e2;
        fr[3][3] = l3 * e0 * u2 + l4 * e1 * u4 + l5 * e2 * u5 + e3;

        // M = fr @ matrix[b,c]  (row-major [4][4])
        const float* mt = matrix + ((b << 3) + c) * 16;
#pragma unroll
        for (int i = 0; i < 4; ++i) {
#pragma unroll
            for (int k = 0; k < 4; ++k) {
                m5[i * 4 + k][f] = fr[i][0] * mt[0 * 4 + k]
                                 + fr[i][1] * mt[1 * 4 + k]
                                 + fr[i][2] * mt[2 * 4 + k]
                                 + fr[i][3] * mt[3 * 4 + k];
            }
        }
    }
    __syncthreads();

    // Each thread's frequency is fixed across its KU elements: f = t & 31.
    const int f = t & (NUM_FREQ - 1);
    const float m00 = m5[ 0][f], m01 = m5[ 1][f], m02 = m5[ 2][f], m03 = m5[ 3][f];
    const float m10 = m5[ 4][f], m11 = m5[ 5][f], m12 = m5[ 6][f], m13 = m5[ 7][f];
    const float m20 = m5[ 8][f], m21 = m5[ 9][f], m22 = m5[10][f], m23 = m5[11][f];
    const float m30 = m5[12][f], m31 = m5[13][f], m32 = m5[14][f], m33 = m5[15][f];

#pragma unroll
    for (int k = 0; k < KU; ++k) {
        vfloat4 o;
        o.x = m00 * v[k].x + m01 * v[k].y + m02 * v[k].z + m03 * v[k].w;
        o.y = m10 * v[k].x + m11 * v[k].y + m12 * v[k].z + m13 * v[k].w;
        o.z = m20 * v[k].x + m21 * v[k].y + m22 * v[k].z + m23 * v[k].w;
        o.w = m30 * v[k].x + m31 * v[k].y + m32 * v[k].z + m33 * v[k].w;
        __builtin_nontemporal_store(o, &out[base + k * 256 + t]);
    }
}

extern "C" void kernel_launch(void* const* d_in, const int* in_sizes, int n_in,
                              void* d_out, int out_size, void* d_ws, size_t ws_size,
                              hipStream_t stream) {
    const float* feats    = (const float*)d_in[0];
    const float* matrix   = (const float*)d_in[1];
    const float* L_params = (const float*)d_in[2];
    const float* D_params = (const float*)d_in[3];
    const float* U_params = (const float*)d_in[4];
    float* out = (float*)d_out;

    const int total4 = (4 * 16 * 4096 * 128) / 4;   // 8,388,608 float4
    const int block  = 256;
    const int grid   = total4 / (block * KU);       // 8192 blocks
    camfreq_fused_kernel<<<grid, block, 0, stream>>>(
        reinterpret_cast<const vfloat4*>(feats), matrix, L_params, D_params,
        U_params, reinterpret_cast<vfloat4*>(out));
}